// Round 12
// baseline (25.698 us; speedup 1.0000x reference)
//
#include <hip/hip_runtime.h>

// FK over the SMPL joint tree — double-buffered counted-vmcnt prefetch on
// the proven 28-frame half-split tile (R11 compute, unchanged).
//
// 1280 persistent single-wave blocks (5/CU; LDS 2x14784 = 29568 B),
// grid-stride over 3584 tiles. Per iteration:
//   s_waitcnt vmcnt(15)   -> tile t's 15 DMAs done (15 newer ops = t-1's
//                            stores may stay in flight; never drain to 0)
//   stage(t+G) into buf^1 -> next tile's loads outstanding during compute
//   compute(t)            -> half-split: lanes 0-31 joints 0-10, lanes
//                            32-63 joints 11-21 of frame fi=lane&31 (<28);
//                            Rg8/Rg9 handoff via __shfl_xor(.,32)
//   store(t)              -> 15 coalesced float4 stores (fire-and-forget)
// NO __syncthreads in the loop (it drains vmcnt(0) and kills the pipeline);
// single-wave blocks only need the asm waitcnts.

#define TPB 64
#define TILE_FRAMES 28
#define TILE_FLOATS (TILE_FRAMES * 132)  // 3696 floats = 14784 B

__device__ __forceinline__ void local_rot(const float* s, float* L) {
    float a1x = s[0], a1y = s[1], a1z = s[2];
    float a2x = s[3], a2y = s[4], a2z = s[5];
    float n1 = sqrtf(a1x * a1x + a1y * a1y + a1z * a1z);
    float i1 = 1.0f / fmaxf(n1, 1e-12f);
    float b1x = a1x * i1, b1y = a1y * i1, b1z = a1z * i1;
    float dt = b1x * a2x + b1y * a2y + b1z * a2z;
    float cx = a2x - dt * b1x, cy = a2y - dt * b1y, cz = a2z - dt * b1z;
    float n2 = sqrtf(cx * cx + cy * cy + cz * cz);
    float i2 = 1.0f / fmaxf(n2, 1e-12f);
    L[0] = b1x; L[1] = b1y; L[2] = b1z;
    L[3] = cx * i2; L[4] = cy * i2; L[5] = cz * i2;
    L[6] = L[1] * L[5] - L[2] * L[4];
    L[7] = L[2] * L[3] - L[0] * L[5];
    L[8] = L[0] * L[4] - L[1] * L[3];
}

__device__ __forceinline__ void matmul3(float* G, const float* P, const float* L) {
#pragma unroll
    for (int r = 0; r < 3; ++r)
#pragma unroll
        for (int c = 0; c < 3; ++c)
            G[3 * r + c] = P[3 * r + 0] * L[0 + c] +
                           P[3 * r + 1] * L[3 + c] +
                           P[3 * r + 2] * L[6 + c];
}

// 15 DMA instructions: 14 full 1024B chunks + 448B tail (lanes 0-27).
__device__ __forceinline__ void stage_tile(const float* __restrict__ in,
                                           int tile, float* buf, int lane) {
    const float* gin = in + (size_t)tile * TILE_FLOATS;
#pragma unroll
    for (int k = 0; k < 14; ++k)
        __builtin_amdgcn_global_load_lds(
            (const __attribute__((address_space(1))) void*)(gin + k * 256 + lane * 4),
            (__attribute__((address_space(3))) void*)(buf + k * 256), 16, 0, 0);
    if (lane < TILE_FRAMES)
        __builtin_amdgcn_global_load_lds(
            (const __attribute__((address_space(1))) void*)(gin + 3584 + lane * 4),
            (__attribute__((address_space(3))) void*)(buf + 3584), 16, 0, 0);
}

// R11's proven half-split compute, in place in buf.
__device__ __forceinline__ void compute_tile(float* buf, int lane) {
    const int half = lane >> 5;      // 0: joints 0-10, 1: joints 11-21
    const int fi = lane & 31;        // frame index (valid < 28)
    const bool act = (fi < TILE_FRAMES);

    float* base = buf + fi * 132;
    const float* src = base + 66 * half;

    float L[11][9];
    if (act) {
#pragma unroll
        for (int i = 0; i < 11; ++i) local_rot(src + 6 * i, L[i]);
    }

    float e8[9], e9[9];
    if (act && half == 0) {
        float Rg[11][9];
#pragma unroll
        for (int k = 0; k < 9; ++k) Rg[0][k] = L[0][k];
        matmul3(Rg[1], Rg[0], L[1]);
        matmul3(Rg[2], Rg[0], L[2]);
        matmul3(Rg[3], Rg[0], L[3]);
        matmul3(Rg[4], Rg[1], L[4]);
        matmul3(Rg[5], Rg[2], L[5]);
        matmul3(Rg[6], Rg[3], L[6]);
        matmul3(Rg[7], Rg[4], L[7]);
        matmul3(Rg[8], Rg[5], L[8]);
        matmul3(Rg[9], Rg[6], L[9]);
        matmul3(Rg[10], Rg[7], L[10]);
#pragma unroll
        for (int i = 0; i < 11; ++i)
#pragma unroll
            for (int k = 0; k < 6; ++k) base[6 * i + k] = Rg[i][k];
#pragma unroll
        for (int k = 0; k < 9; ++k) { e8[k] = Rg[8][k]; e9[k] = Rg[9][k]; }
    }

#pragma unroll
    for (int k = 0; k < 9; ++k) {
        e8[k] = __shfl_xor(e8[k], 32, 64);
        e9[k] = __shfl_xor(e9[k], 32, 64);
    }

    if (act && half == 1) {
        float Rg[11][9];  // local idx i = joint 11+i
        matmul3(Rg[0], e8, L[0]);       // j11 <- j8
        matmul3(Rg[1], e9, L[1]);       // j12 <- j9
        matmul3(Rg[2], e9, L[2]);       // j13 <- j9
        matmul3(Rg[3], e9, L[3]);       // j14 <- j9
        matmul3(Rg[4], Rg[1], L[4]);    // j15 <- j12
        matmul3(Rg[5], Rg[2], L[5]);    // j16 <- j13
        matmul3(Rg[6], Rg[3], L[6]);    // j17 <- j14
        matmul3(Rg[7], Rg[5], L[7]);    // j18 <- j16
        matmul3(Rg[8], Rg[6], L[8]);    // j19 <- j17
        matmul3(Rg[9], Rg[7], L[9]);    // j20 <- j18
        matmul3(Rg[10], Rg[8], L[10]);  // j21 <- j19
#pragma unroll
        for (int i = 0; i < 11; ++i)
#pragma unroll
            for (int k = 0; k < 6; ++k) base[66 + 6 * i + k] = Rg[i][k];
    }
}

__global__ __launch_bounds__(TPB) void fk6d_kernel(const float* __restrict__ in,
                                                   float* __restrict__ out,
                                                   int NT, int G)
{
    __shared__ float lds[2][TILE_FLOATS];  // 29568 B -> 5 blocks/CU
    const int lane = threadIdx.x;

    int t = blockIdx.x;
    if (t < NT) stage_tile(in, t, lds[0], lane);

    int cur = 0;
    bool first = true;
    for (; t < NT; t += G) {
        // tile t's 15 loads done; up to 15 newer ops (prev stores) in flight
        if (first) {
            asm volatile("s_waitcnt vmcnt(0)" ::: "memory");
            first = false;
        } else {
            asm volatile("s_waitcnt vmcnt(15)" ::: "memory");
        }

        int nxt = t + G;
        if (nxt < NT) stage_tile(in, nxt, lds[cur ^ 1], lane);
        asm volatile("" ::: "memory");  // pin DMA issue before compute/stores

        compute_tile(lds[cur], lane);
        asm volatile("s_waitcnt lgkmcnt(0)" ::: "memory");  // LDS writes visible

        // 15 coalesced store instructions: 14 full float4 rounds + tail
        float* gdst = out + (size_t)t * TILE_FLOATS;
        const float4* l4 = reinterpret_cast<const float4*>(lds[cur]);
        float4* o4 = reinterpret_cast<float4*>(gdst);
#pragma unroll
        for (int k = 0; k < 14; ++k) o4[k * 64 + lane] = l4[k * 64 + lane];
        if (lane < TILE_FRAMES) o4[896 + lane] = l4[896 + lane];

        cur ^= 1;
    }
}

// scalar tail (not taken: 100352 % 28 == 0)
__global__ void fk6d_tail(const float* __restrict__ in, float* __restrict__ out,
                          int n0, int N) {
    constexpr int PAR[22] = {0, 0, 0, 0, 1, 2, 3, 4, 5, 6, 7, 8, 9, 9, 9,
                             12, 13, 14, 16, 17, 18, 19};
    int n = n0 + blockIdx.x * blockDim.x + threadIdx.x;
    if (n >= N) return;
    const float* src = in + (size_t)n * 132;
    float* dst = out + (size_t)n * 132;
    float Rg[22][9];
#pragma unroll
    for (int j = 0; j < 22; ++j) {
        float Lr[9];
        local_rot(src + 6 * j, Lr);
        if (j == 0) {
#pragma unroll
            for (int k = 0; k < 9; ++k) Rg[0][k] = Lr[k];
        } else {
            matmul3(Rg[j], Rg[PAR[j]], Lr);
        }
#pragma unroll
        for (int k = 0; k < 6; ++k) dst[6 * j + k] = Rg[j][k];
    }
}

extern "C" void kernel_launch(void* const* d_in, const int* in_sizes, int n_in,
                              void* d_out, int out_size, void* d_ws, size_t ws_size,
                              hipStream_t stream) {
    const float* in = (const float*)d_in[0];
    float* out = (float*)d_out;
    int N = in_sizes[0] / 132;        // 100352 frames
    int NT = N / TILE_FRAMES;         // 3584 full tiles
    int G = 1280;                     // 5 blocks/CU on 256 CUs, persistent
    if (G > NT) G = (NT > 0 ? NT : 1);
    if (NT > 0) fk6d_kernel<<<G, TPB, 0, stream>>>(in, out, NT, G);
    int rem = N - NT * TILE_FRAMES;
    if (rem > 0)
        fk6d_tail<<<(rem + 63) / 64, 64, 0, stream>>>(in, out, NT * TILE_FRAMES, N);
}